// Round 8
// baseline (353.107 us; speedup 1.0000x reference)
//
#include <hip/hip_runtime.h>

typedef _Float16 f16;
typedef __attribute__((ext_vector_type(8))) _Float16 half8;
typedef __attribute__((ext_vector_type(4))) _Float16 half4v;
typedef __attribute__((ext_vector_type(4))) float floatx4;

#define T_DIM 2048
#define HID   2048
#define NH    16
#define HD    128
#define QG_LD 2064
#define SM_SCALE 0.08838834764831845f   // 1/sqrt(128)
#define NEG_BIG  -1e30f

// ---------------------------------------------------------------- async copy
__device__ __forceinline__ void async16(const void* g, void* l) {
  __builtin_amdgcn_global_load_lds((const __attribute__((address_space(1))) void*)g,
                                   (__attribute__((address_space(3))) void*)l, 16, 0, 0);
}

// ================================================= fused prep v4: transposes + convert + gate
// Grid (64, 32, 6).
// z=0..3: Wq/Wk/Wv/Wo fp32->f16 transpose, 64(K)x32(N) tiles, f16-pair u32 packing.
// z=4: hidden f32->f16 convert. z=5: gate fp64 dot (sign only), LDS-FREE:
//   each wave owns 4 heads, float4 loads, fp64 FMA, 6-step shfl_xor(double) butterfly.
// v4 change: static LDS 34816 -> 4224 B. The old gate reduction buffer capped the WHOLE
// kernel at 4 blocks/CU (LDS_Block_Size=34816, Occupancy ~37%); now wave-limited 8/CU.
__global__ __launch_bounds__(256) void prep_all(const float* __restrict__ Wq,
                                                const float* __restrict__ Wk,
                                                const float* __restrict__ Wv,
                                                const float* __restrict__ Wo,
                                                const float* __restrict__ hidden,
                                                f16* __restrict__ WqT, f16* __restrict__ WkT,
                                                f16* __restrict__ WvT, f16* __restrict__ WoT,
                                                f16* __restrict__ hidh, float* __restrict__ gate) {
  __shared__ __align__(16) char smem[4224];       // transpose tile only
  const int z = blockIdx.z;
  const int tx = threadIdx.x, ty = threadIdx.y;
  const int tid = ty * 32 + tx;
  if (z == 4) {
    const int lb = blockIdx.y * 64 + blockIdx.x;   // 0..2047
#pragma unroll
    for (int e = 0; e < 2; ++e) {
      const int i = lb * 2048 + e * 1024 + tid * 4;
      const float4 v = *(const float4*)(hidden + i);
      half4v o;
      o.x = (f16)v.x; o.y = (f16)v.y; o.z = (f16)v.z; o.w = (f16)v.w;
      *(half4v*)(hidh + i) = o;
    }
    return;
  }
  if (z == 5) {
    // gate: wave wv owns heads 4wv..4wv+3; no LDS, no __syncthreads
    const int t = blockIdx.y * 64 + blockIdx.x;   // 0..2047
    const int lane = tid & 63;
    const int wv = tid >> 6;
    const float* hrow = hidden + (size_t)t * HID;
    const float* wbase = Wq + 2048 + 4 * wv;      // gate cols of Wq, head group base
    double s0 = 0.0, s1 = 0.0, s2 = 0.0, s3 = 0.0;
#pragma unroll
    for (int e = 0; e < 8; ++e) {
      const int k0 = e * 256 + lane * 4;
      const float4 hv = *(const float4*)(hrow + k0);
      const float4 a = *(const float4*)(wbase + (size_t)(k0 + 0) * QG_LD);
      const float4 b = *(const float4*)(wbase + (size_t)(k0 + 1) * QG_LD);
      const float4 c = *(const float4*)(wbase + (size_t)(k0 + 2) * QG_LD);
      const float4 d = *(const float4*)(wbase + (size_t)(k0 + 3) * QG_LD);
      s0 += (double)hv.x * (double)a.x; s1 += (double)hv.x * (double)a.y;
      s2 += (double)hv.x * (double)a.z; s3 += (double)hv.x * (double)a.w;
      s0 += (double)hv.y * (double)b.x; s1 += (double)hv.y * (double)b.y;
      s2 += (double)hv.y * (double)b.z; s3 += (double)hv.y * (double)b.w;
      s0 += (double)hv.z * (double)c.x; s1 += (double)hv.z * (double)c.y;
      s2 += (double)hv.z * (double)c.z; s3 += (double)hv.z * (double)c.w;
      s0 += (double)hv.w * (double)d.x; s1 += (double)hv.w * (double)d.y;
      s2 += (double)hv.w * (double)d.z; s3 += (double)hv.w * (double)d.w;
    }
#pragma unroll
    for (int off = 32; off > 0; off >>= 1) {
      s0 += __shfl_xor(s0, off, 64);
      s1 += __shfl_xor(s1, off, 64);
      s2 += __shfl_xor(s2, off, 64);
      s3 += __shfl_xor(s3, off, 64);
    }
    if (lane == 0) {
      float* g = gate + (size_t)t * 16 + 4 * wv;
      g[0] = (s0 > 0.0) ? 1.f : 0.f;
      g[1] = (s1 > 0.0) ? 1.f : 0.f;
      g[2] = (s2 > 0.0) ? 1.f : 0.f;
      g[3] = (s3 > 0.0) ? 1.f : 0.f;
    }
    return;
  }
  // z = 0..3: fp32 -> f16 transpose with pair packing
  unsigned (*tile)[33] = (unsigned (*)[33])smem;  // 32*33*4 = 4224 B
  const float* src = (z == 0) ? Wq : ((z == 1) ? Wk : ((z == 2) ? Wv : Wo));
  const int ld = (z == 0) ? QG_LD : 2048;
  f16* dst = (z == 0) ? WqT : ((z == 1) ? WkT : ((z == 2) ? WvT : WoT));
  const int nb = blockIdx.x * 32;                 // N block (32 cols)
  const int kb = blockIdx.y * 64;                 // K block (64 rows = 32 pairs)
#pragma unroll
  for (int i = 0; i < 4; ++i) {
    const int kp = ty + 8 * i;                    // pair index 0..31
    const float lo = src[(size_t)(kb + 2 * kp) * ld + nb + tx];
    const float hi = src[(size_t)(kb + 2 * kp + 1) * ld + nb + tx];
    union { f16 h[2]; unsigned u; } cv;
    cv.h[0] = (f16)lo; cv.h[1] = (f16)hi;
    tile[kp][tx] = cv.u;
  }
  __syncthreads();
#pragma unroll
  for (int i = 0; i < 4; ++i) {
    const int n = ty + 8 * i;                     // output row within N-block
    *(unsigned*)&dst[(size_t)(nb + n) * HID + kb + 2 * tx] = tile[tx][n];
  }
}

// ================================================= fused post-QKV: RMSNorm+RoPE  |  V transpose
// blocks 0..4095: norm_rope (q & k). blocks 4096..8191: f16 V transpose (32x32 tiles).
__global__ __launch_bounds__(256) void post_qkv(const f16* __restrict__ qsrc, const f16* __restrict__ ksrc,
                                                const float* __restrict__ qw, const float* __restrict__ kw,
                                                const int* __restrict__ pos,
                                                f16* __restrict__ qdst, f16* __restrict__ kdst,
                                                const f16* __restrict__ vsrc, f16* __restrict__ vdst) {
  __shared__ __align__(16) char smem[9216];
  const int b = blockIdx.x;
  const int tid = threadIdx.x;
  if (b >= 4096) {
    f16 (*tile)[33] = (f16 (*)[33])smem;        // 32*33*2 = 2112 B
    const int u = b - 4096;
    const int bx = (u & 63) * 32, by = (u >> 6) * 32;
    const int tx = tid & 31, ty = tid >> 5;
#pragma unroll
    for (int i = 0; i < 4; ++i)
      tile[ty + 8 * i][tx] = vsrc[(size_t)(by + ty + 8 * i) * T_DIM + bx + tx];
    __syncthreads();
#pragma unroll
    for (int i = 0; i < 4; ++i)
      vdst[(size_t)(bx + ty + 8 * i) * T_DIM + by + tx] = tile[tx][ty + 8 * i];
    return;
  }
  float* row = (float*)smem;                    // 2048 f32 = 8192 B
  float* red = (float*)(smem + 8192);           // 256 f32 = 1024 B
  const int t = b & 2047, sel = b >> 11;
  const f16* s = (sel ? ksrc : qsrc) + (size_t)t * HID;
  const float* w = sel ? kw : qw;
  f16* dst = sel ? kdst : qdst;
  float ss = 0.f;
#pragma unroll
  for (int e = 0; e < 8; ++e) {
    float v = (float)s[tid + 256 * e];
    row[tid + 256 * e] = v;
    ss += v * v;
  }
  red[tid] = ss;
  __syncthreads();
  for (int st = 128; st > 0; st >>= 1) {
    if (tid < st) red[tid] += red[tid + st];
    __syncthreads();
  }
  const float scl = rsqrtf(red[0] * (1.f / 2048.f) + 1e-6f);
  const float p = (float)pos[t];
#pragma unroll
  for (int e = 0; e < 8; ++e) {
    const int idx = tid + 256 * e;
    const int d = idx & 127;
    const int dh = d & 63;
    const int pidx = (d < 64) ? idx + 64 : idx - 64;
    const float xn = row[idx] * scl * w[idx];
    const float xp = row[pidx] * scl * w[pidx];
    const float inv = __expf(-(float)dh * 0.20503692772194388f);
    float cs, sn;
    sincosf(p * inv, &sn, &cs);
    const float o = (d < 64) ? (xn * cs - xp * sn) : (xn * cs + xp * sn);
    dst[(size_t)t * HID + idx] = (f16)o;
  }
}

#define LGKM0() asm volatile("s_waitcnt lgkmcnt(0)" ::: "memory")
#define BAR()   __builtin_amdgcn_s_barrier()
#define PRIO(x) __builtin_amdgcn_s_setprio(x)

// ------------------------------------------------- GEMM 128x128xBK64, double-buffered (gemm_out_sk)
__device__ __forceinline__ void gemm_issue(const f16* __restrict__ A, const f16* __restrict__ Bt,
                                           char* As, char* Bs, int m0, int n0, int k0,
                                           int wave, int srow, int scol) {
#pragma unroll
  for (int i = 0; i < 4; ++i) {
    async16(A + (size_t)(m0 + 32 * i + srow) * 2048 + k0 + scol, As + 4096 * i + 1024 * wave);
    async16(Bt + (size_t)(n0 + 32 * i + srow) * 2048 + k0 + scol, Bs + 4096 * i + 1024 * wave);
  }
}

__device__ __forceinline__ void gemm_core_db(const f16* __restrict__ A, const f16* __restrict__ Bt,
                                             f16* As, f16* Bs, floatx4 (&acc)[4][4],
                                             int kbase, int klen) {
  const int tid = threadIdx.x;
  const int lane = tid & 63, wave = tid >> 6;
  const int m0 = blockIdx.y * 128, n0 = blockIdx.x * 128;
  const int mo = (wave >> 1) * 64, no = (wave & 1) * 64;
  const int cn = lane & 15, q16 = lane >> 4;
  const int srow = 8 * wave + (lane >> 3);
  const int scol = (lane & 7) * 8;
  gemm_issue(A, Bt, (char*)As, (char*)Bs, m0, n0, kbase, wave, srow, scol);
  int cur = 0;
  for (int k0 = kbase; k0 < kbase + klen; k0 += 64) {
    __syncthreads();
    if (k0 + 64 < kbase + klen)
      gemm_issue(A, Bt, (char*)(As + (cur ^ 1) * 8192), (char*)(Bs + (cur ^ 1) * 8192),
                 m0, n0, k0 + 64, wave, srow, scol);
    const f16* as = As + cur * 8192;
    const f16* bs = Bs + cur * 8192;
#pragma unroll
    for (int kk = 0; kk < 64; kk += 32) {
      half8 av[4], bv[4];
#pragma unroll
      for (int i = 0; i < 4; ++i) av[i] = *(const half8*)&as[(mo + i * 16 + cn) * 64 + kk + q16 * 8];
#pragma unroll
      for (int i = 0; i < 4; ++i) bv[i] = *(const half8*)&bs[(no + i * 16 + cn) * 64 + kk + q16 * 8];
#pragma unroll
      for (int i = 0; i < 4; ++i)
#pragma unroll
        for (int j = 0; j < 4; ++j)
          acc[i][j] = __builtin_amdgcn_mfma_f32_16x16x32_f16(av[i], bv[j], acc[i][j], 0, 0, 0);
    }
    cur ^= 1;
  }
}

// ================================================= 256x192 8-phase fused QKV GEMM
// One GEMM: M=2048, N=6144 (WqT|WkT|WvT contiguous), K=2048. BM=256, BN=192, BK=64.
// Grid (32,8) = 256 blocks. 8 waves (2Mx4N), wave tile 128x48. 112 KiB LDS dbuf.
#define NKT 32

__device__ __forceinline__ void stage_piece(const f16* __restrict__ src, int row0, int kcol,
                                            char* dst, int wv, int lane) {
  const int rsw = lane >> 3;
  const int csw = ((lane & 7) ^ rsw) << 3;
  async16(src + (size_t)(row0 + wv * 8 + rsw) * 2048 + kcol + csw, dst + wv * 1024);
}

template <int MQ, int KH>
__device__ __forceinline__ void ld_a1(half8 (&a)[4], const f16* As, int wm, int cn, int q16) {
#pragma unroll
  for (int rf = 0; rf < 4; ++rf) {
    const int R = wm * 128 + MQ * 64 + rf * 16 + cn;
    a[rf] = *(const half8*)&As[R * 64 + (((KH * 4 + q16) ^ (cn & 7)) << 3)];
  }
}

template <int KH>
__device__ __forceinline__ void ld_b3(half8 (&b)[3], const f16* Bs, int wn, int cn, int q16) {
#pragma unroll
  for (int cf = 0; cf < 3; ++cf) {
    const int S = wn * 48 + cf * 16 + cn;
    b[cf] = *(const half8*)&Bs[S * 64 + (((KH * 4 + q16) ^ (cn & 7)) << 3)];
  }
}

template <int MQ>
__device__ __forceinline__ void mma12(floatx4 (&acc)[8][3], const half8 (&a)[4], const half8 (&b)[3]) {
#pragma unroll
  for (int rf = 0; rf < 4; ++rf)
#pragma unroll
    for (int cf = 0; cf < 3; ++cf)
      acc[MQ * 4 + rf][cf] = __builtin_amdgcn_mfma_f32_16x16x32_f16(
          a[rf], b[cf], acc[MQ * 4 + rf][cf], 0, 0, 0);
}

#define QKV_A(q, kt, buf) stage_piece(A,  m0 + (q) * 64, (kt) * 64, ldsb + (buf) * 57344 + (q) * 8192, wv, lane)
#define QKV_B(p, kt, buf) stage_piece(BT, n0 + (p) * 64, (kt) * 64, ldsb + (buf) * 57344 + 32768 + (p) * 8192, wv, lane)

__global__ __launch_bounds__(512, 2) void gemm_qkv192(const f16* __restrict__ A,
                                                      const f16* __restrict__ BT,   // [6144][2048]
                                                      f16* __restrict__ Call) {     // 3x [2048][2048] contiguous
  __shared__ __align__(16) f16 lds[57344];  // 112 KiB
  char* const ldsb = (char*)lds;
  const int tid = threadIdx.x;
  const int lane = tid & 63, wv = tid >> 6;
  const int wm = wv >> 2, wn = wv & 3;
  const int q16 = lane >> 4, cn = lane & 15;
  const int m0 = blockIdx.y * 256, n0 = blockIdx.x * 192;

  floatx4 acc[8][3] = {};
  half8 a[4], b0[3], b1[3];

  // prologue: t0 all 7 pieces, then t1 in steady issue order
  QKV_B(0, 0, 0); QKV_B(1, 0, 0); QKV_B(2, 0, 0); QKV_A(0, 0, 0); QKV_A(2, 0, 0);
  QKV_A(1, 0, 0); QKV_A(3, 0, 0);
  QKV_B(0, 1, 1); QKV_B(1, 1, 1); QKV_B(2, 1, 1); QKV_A(0, 1, 1); QKV_A(2, 1, 1);
  QKV_A(1, 1, 1); QKV_A(3, 1, 1);
  asm volatile("s_waitcnt vmcnt(7)" ::: "memory");
  BAR();

  for (int t = 0; t < NKT; ++t) {
    const int pb = t & 1;
    const f16* As = lds + pb * 28672;
    const f16* Bs = As + 16384;
    // ---- P1 (MQ0, kh0)
    ld_b3<0>(b0, Bs, wn, cn, q16);
    ld_a1<0, 0>(a, As, wm, cn, q16);
    if (t >= 1 && t + 1 < NKT) QKV_A(1, t + 1, pb ^ 1);
    asm volatile("s_waitcnt vmcnt(6)" ::: "memory");
    BAR(); LGKM0();
    PRIO(1); mma12<0>(acc, a, b0); PRIO(0);
    BAR();
    // ---- P2 (MQ1, kh0)
    ld_a1<1, 0>(a, As, wm, cn, q16);
    if (t >= 1 && t + 1 < NKT) QKV_A(3, t + 1, pb ^ 1);
    BAR(); LGKM0();
    PRIO(1); mma12<1>(acc, a, b0); PRIO(0);
    BAR();
    // ---- P3 (MQ0, kh1)
    ld_b3<1>(b1, Bs, wn, cn, q16);
    ld_a1<0, 1>(a, As, wm, cn, q16);
    BAR(); LGKM0();
    PRIO(1); mma12<0>(acc, a, b1); PRIO(0);
    BAR();
    // ---- P4 (MQ1, kh1)
    ld_a1<1, 1>(a, As, wm, cn, q16);
    if (t + 2 < NKT) {
      QKV_B(0, t + 2, pb); QKV_B(1, t + 2, pb); QKV_B(2, t + 2, pb);
      QKV_A(0, t + 2, pb); QKV_A(2, t + 2, pb);
      asm volatile("s_waitcnt vmcnt(7)" ::: "memory");
    } else if (t == NKT - 2) {
      asm volatile("s_waitcnt vmcnt(0)" ::: "memory");
    }
    BAR(); LGKM0();
    PRIO(1); mma12<1>(acc, a, b1); PRIO(0);
    BAR();
  }

  // epilogue: output buffer = global col >> 11 (16-col frags never straddle: bases 16-aligned)
  const int r0 = q16 * 4;
#pragma unroll
  for (int j = 0; j < 3; ++j) {
    const int cb = n0 + wn * 48 + j * 16;
    f16* Cj = Call + ((size_t)(cb >> 11) << 22) + (cb & 2047) + cn;
#pragma unroll
    for (int i = 0; i < 8; ++i)
#pragma unroll
      for (int r = 0; r < 4; ++r)
        Cj[(size_t)(m0 + wm * 128 + i * 16 + r0 + r) * 2048] = (f16)acc[i][j][r];
  }
}

// split-K=2 attention-output GEMM: z picks K-half, writes fp32 partial (r3-proven)
__global__ __launch_bounds__(256, 2) void gemm_out_sk(const f16* __restrict__ A, const f16* __restrict__ Bt,
                                                      float* __restrict__ P0, float* __restrict__ P1) {
  __shared__ __align__(16) f16 As[2 * 128 * 64];
  __shared__ __align__(16) f16 Bs[2 * 128 * 64];
  const int z = blockIdx.z;
  floatx4 acc[4][4] = {};
  gemm_core_db(A, Bt, As, Bs, acc, z * 1024, 1024);
  float* C = z ? P1 : P0;
  const int lane = threadIdx.x & 63, wave = threadIdx.x >> 6;
  const int mb = blockIdx.y * 128 + (wave >> 1) * 64;
  const int nb = blockIdx.x * 128 + (wave & 1) * 64;
  const int r0 = (lane >> 4) * 4, cn = lane & 15;
#pragma unroll
  for (int i = 0; i < 4; ++i)
#pragma unroll
    for (int j = 0; j < 4; ++j)
#pragma unroll
      for (int r = 0; r < 4; ++r)
        C[(size_t)(mb + i * 16 + r0 + r) * 2048 + nb + j * 16 + cn] = acc[i][j][r];
}

__global__ __launch_bounds__(256) void add_out(const float* __restrict__ P0, const float* __restrict__ P1,
                                               float* __restrict__ out) {
  const int i = (blockIdx.x * 256 + threadIdx.x) * 4;
  const float4 a = *(const float4*)(P0 + i);
  const float4 b = *(const float4*)(P1 + i);
  float4 o;
  o.x = a.x + b.x; o.y = a.y + b.y; o.z = a.z + b.z; o.w = a.w + b.w;
  *(float4*)(out + i) = o;
}

// ------------------------------------------------- dual flash attention v5: split-K load balance
__global__ __launch_bounds__(256, 2) void flash_kernel(const f16* __restrict__ Qg, const f16* __restrict__ Kg,
                                                       const f16* __restrict__ VTg, const float* __restrict__ gate,
                                                       f16* __restrict__ Oa, float* __restrict__ Opart,
                                                       float2* __restrict__ ml) {
  __shared__ __align__(16) f16 Ks[2][64 * 128];    // [s][d], granule-swizzled
  __shared__ __align__(16) f16 VTs[2][128 * 64];   // [d][s], granule-swizzled
  __shared__ __align__(16) f16 Ps[4][16][72];      // wave-private, 144B stride

  const int tid = threadIdx.x;
  const int lane = tid & 63, wv = tid >> 6;
  const int q16 = lane >> 4, cn = lane & 15;
  const int r0 = q16 * 4;

  // ---- chunk decode: p -> (h, qt, [kb,ke], slot) ; ordered big-work-first
  const int p = blockIdx.x;
  const int o = p >> 4;
  const int h = p & 15;
  int qt, nsp, piece, slot_o;
  if (o < 24)      { qt = 31 - o / 3;        nsp = 3; piece = o % 3;        slot_o = o; }
  else if (o < 36) { qt = 35 - o;            nsp = 1; piece = 0;            slot_o = 0; }
  else             { int u = o - 36; qt = 23 - (u >> 1); nsp = 2; piece = u & 1; slot_o = 24 + u; }
  const int L = qt + 1;
  const int base = L / nsp, rem = L % nsp;
  const int kb = piece * base + (piece < rem ? piece : rem);
  const int ke = kb + base + (piece < rem ? 1 : 0) - 1;
  const bool split = (nsp > 1);
  const int slot = h * 48 + slot_o;
  const int t0 = qt * 64;

  bool gbit[4];
#pragma unroll
  for (int r = 0; r < 4; ++r)
    gbit[r] = gate[(size_t)(t0 + wv * 16 + r0 + r) * NH + h] > 0.5f;

  half8 qa[4];
#pragma unroll
  for (int i = 0; i < 4; ++i)
    qa[i] = *(const half8*)(Qg + (size_t)(t0 + 16 * wv + cn) * HID + h * HD + 32 * i + q16 * 8);

  {
    const int sb = kb * 64;
#pragma unroll
    for (int i = 0; i < 4; ++i) {
      const int rk = 16 * i + 4 * wv + q16;
      async16(Kg + (size_t)(sb + rk) * HID + h * HD + ((cn ^ (rk & 7)) << 3),
              (char*)Ks[0] + 4096 * i + 1024 * wv);
      const int rv = 32 * i + 8 * wv + (lane >> 3);
      async16(VTg + (size_t)(h * HD + rv) * T_DIM + sb + (((lane & 7) ^ (lane >> 3)) << 3),
              (char*)VTs[0] + 4096 * i + 1024 * wv);
    }
  }

  floatx4 og[8] = {};
  floatx4 lacc = {0.f, 0.f, 0.f, 0.f};
  float mg[4];
#pragma unroll
  for (int r = 0; r < 4; ++r) mg[r] = NEG_BIG;

  const half8 ones = {(f16)1, (f16)1, (f16)1, (f16)1, (f16)1, (f16)1, (f16)1, (f16)1};

  int cur = 0;
  for (int kt = kb; kt <= ke; ++kt) {
    const int s0 = kt * 64;
    __syncthreads();
    if (kt < ke) {
      const int sn = s0 + 64;
#pragma unroll
      for (int i = 0; i < 4; ++i) {
        const int rk = 16 * i + 4 * wv + q16;
        async16(Kg + (size_t)(sn + rk) * HID + h * HD + ((cn ^ (rk & 7)) << 3),
                (char*)Ks[cur ^ 1] + 4096 * i + 1024 * wv);
        const int rv = 32 * i + 8 * wv + (lane >> 3);
        async16(VTg + (size_t)(h * HD + rv) * T_DIM + sn + (((lane & 7) ^ (lane >> 3)) << 3),
                (char*)VTs[cur ^ 1] + 4096 * i + 1024 * wv);
      }
    }

    // S = Q K^T : wave wv owns rows [16wv, 16wv+16)
    floatx4 sacc[4] = {};
    PRIO(1);
#pragma unroll
    for (int i = 0; i < 4; ++i)
#pragma unroll
      for (int nt = 0; nt < 4; ++nt) {
        half8 b = *(const half8*)&Ks[cur][(nt * 16 + cn) * 128 + (((4 * i + q16) ^ (cn & 7)) << 3)];
        sacc[nt] = __builtin_amdgcn_mfma_f32_16x16x32_f16(qa[i], b, sacc[nt], 0, 0, 0);
      }
    PRIO(0);

    const bool diag = (kt == qt);

    float pe[4][4];
#pragma unroll
    for (int nt = 0; nt < 4; ++nt)
#pragma unroll
      for (int r = 0; r < 4; ++r) {
        float x = sacc[nt][r] * SM_SCALE;
        if (diag && (s0 + nt * 16 + cn > t0 + wv * 16 + r0 + r)) x = NEG_BIG;
        pe[nt][r] = x;
      }

    float rmax[4];
#pragma unroll
    for (int r = 0; r < 4; ++r)
      rmax[r] = fmaxf(fmaxf(pe[0][r], pe[1][r]), fmaxf(pe[2][r], pe[3][r]));
#pragma unroll
    for (int off = 1; off < 16; off <<= 1)
#pragma unroll
      for (int r = 0; r < 4; ++r) rmax[r] = fmaxf(rmax[r], __shfl_xor(rmax[r], off, 64));

    // defer-rescale: when no row max grows, alpha == 1.0 exactly -> skip is bitwise identical
    const bool grow = (rmax[0] > mg[0]) | (rmax[1] > mg[1]) | (rmax[2] > mg[2]) | (rmax[3] > mg[3]);
    if (__any(grow)) {
      float alpha[4];
#pragma unroll
      for (int r = 0; r < 4; ++r) {
        const float mn = fmaxf(mg[r], rmax[r]);
        alpha[r] = __expf(mg[r] - mn);
        mg[r] = mn;
      }
#pragma unroll
      for (int dt = 0; dt < 8; ++dt)
#pragma unroll
        for (int r = 0; r < 4; ++r) og[dt][r] *= alpha[r];
#pragma unroll
      for (int r = 0; r < 4; ++r) lacc[r] *= alpha[r];
    }

    // exp, gate/window select, store P_sel (wave-private -> no barrier)
#pragma unroll
    for (int nt = 0; nt < 4; ++nt)
#pragma unroll
      for (int r = 0; r < 4; ++r) {
        const float e = __expf(pe[nt][r] - mg[r]);   // causal-masked -> 0
        const int tt = t0 + wv * 16 + r0 + r;
        const int s = s0 + nt * 16 + cn;
        const bool keep = gbit[r] || (tt - s < 128);
        Ps[wv][r0 + r][nt * 16 + cn] = keep ? (f16)e : (f16)0.f;
      }

    // PV + row-sum: A = own P_sel rows
    PRIO(1);
#pragma unroll
    for (int kk = 0; kk < 64; kk += 32) {
      half8 a = *(const half8*)&Ps[wv][cn][kk + q16 * 8];
#pragma unroll
      for (int dt = 0; dt < 8; ++dt) {
        half8 b = *(const half8*)&VTs[cur][(dt * 16 + cn) * 64 + ((((kk >> 3) + q16) ^ (cn & 7)) << 3)];
        og[dt] = __builtin_amdgcn_mfma_f32_16x16x32_f16(a, b, og[dt], 0, 0, 0);
      }
      lacc = __builtin_amdgcn_mfma_f32_16x16x32_f16(a, ones, lacc, 0, 0, 0);
    }
    PRIO(0);
    cur ^= 1;
  }

  if (!split) {
#pragma unroll
    for (int dt = 0; dt < 8; ++dt)
#pragma unroll
      for (int r = 0; r < 4; ++r) {
        const float v = og[dt][r] / lacc[r];
        Oa[(size_t)(t0 + wv * 16 + r0 + r) * HID + h * HD + dt * 16 + cn] = (f16)v;
      }
  } else {
    float* ob = Opart + ((size_t)slot * 64 + wv * 16) * 128;
#pragma unroll
    for (int dt = 0; dt < 8; ++dt)
#pragma unroll
      for (int r = 0; r < 4; ++r)
        ob[(r0 + r) * 128 + dt * 16 + cn] = og[dt][r];
    if (cn == 0) {
      float2* mlp = ml + slot * 64 + wv * 16;
#pragma unroll
      for (int r = 0; r < 4; ++r) mlp[r0 + r] = float2{mg[r], lacc[r]};
    }
  }
}

// ------------------------------------------------- merge split-K partials (qt>=12 only)
__global__ __launch_bounds__(256) void merge_chunks(const float* __restrict__ Opart,
                                                    const float2* __restrict__ ml,
                                                    f16* __restrict__ attn) {
  const int b = blockIdx.x;           // 320 = 16 heads x 20 q-tiles (qt 12..31)
  const int h = b & 15, v = b >> 4;
  const int qt = 12 + v;
  const int n = (qt >= 24) ? 3 : 2;
  const int s0 = (qt >= 24) ? (h * 48 + 3 * (31 - qt)) : (h * 48 + 24 + 2 * (23 - qt));
  const int tid = threadIdx.x;
  const int row = tid >> 2;           // 0..63
  const int cq = (tid & 3) * 32;

  float m = NEG_BIG, mv[3], lv[3];
#pragma unroll
  for (int c = 0; c < 3; ++c) {
    if (c < n) {
      const float2 x = ml[(s0 + c) * 64 + row];
      mv[c] = x.x; lv[c] = x.y;
      m = fmaxf(m, x.x);
    }
  }
  float e[3], denom = 0.f;
#pragma unroll
  for (int c = 0; c < 3; ++c) {
    if (c < n) {
      e[c] = __expf(mv[c] - m);
      denom += e[c] * lv[c];
    }
  }
  const float inv = 1.f / denom;
  f16* out = attn + (size_t)(qt * 64 + row) * 2048 + h * 128 + cq;
#pragma unroll
  for (int i = 0; i < 32; i += 4) {
    float4 acc = {0.f, 0.f, 0.f, 0.f};
#pragma unroll
    for (int c = 0; c < 3; ++c) {
      if (c < n) {
        const float4 a = *(const float4*)(Opart + ((size_t)(s0 + c) * 64 + row) * 128 + cq + i);
        acc.x += e[c] * a.x; acc.y += e[c] * a.y; acc.z += e[c] * a.z; acc.w += e[c] * a.w;
      }
    }
    out[i + 0] = (f16)(acc.x * inv);
    out[i + 1] = (f16)(acc.y * inv);
    out[i + 2] = (f16)(acc.z * inv);
    out[i + 3] = (f16)(acc.w * inv);
  }
}

// ------------------------------------------------------------------ host
extern "C" void kernel_launch(void* const* d_in, const int* in_sizes, int n_in,
                              void* d_out, int out_size, void* d_ws, size_t ws_size,
                              hipStream_t stream) {
  const float* hidden = (const float*)d_in[0];
  const int* pos = (const int*)d_in[1];
  const float* Wq = (const float*)d_in[2];
  const float* Wk = (const float*)d_in[3];
  const float* Wv = (const float*)d_in[4];
  const float* Wo = (const float*)d_in[5];
  const float* qw = (const float*)d_in[6];
  const float* kw = (const float*)d_in[7];

  char* ws = (char*)d_ws;
  const size_t MB = 1ull << 20;
  // Layout (peak ~88.5 MB):
  //  0- 8 WqT (rows 0-2047 of BT_all)
  //  8-16 WkT                     -> dead after QKV: Opart (8-32), later P0 (8-24)
  // 16-24 WvT
  // 24-32 hidh                    -> dead after QKV
  // 32-40 q_raw (Call buf 0)      -> reused as attn after norm
  // 40-48 k_raw (Call buf 1)      -> dead after post_qkv: P1 (40-56)
  // 48-56 v_h   (Call buf 2)      -> dead after post_qkv
  // 56-64 vT                      -> dead after flash
  // 64-72 WoT                     (written at prep, live until gemm_out_sk)
  // 72-80 q_h, 80-88 k_h          -> dead after flash
  // 88.0-88.125 gate, 88.125-88.5 mlbuf
  f16* WqT = (f16*)(ws + 0 * MB);
  f16* WkT = (f16*)(ws + 8 * MB);
  f16* WvT = (f16*)(ws + 16 * MB);
  f16* hidh = (f16*)(ws + 24 * MB);
  f16* q_raw = (f16*)(ws + 32 * MB);
  f16* k_raw = (f16*)(ws + 40 * MB);
  f16* v_h = (f16*)(ws + 48 * MB);
  f16* vT = (f16*)(ws + 56 * MB);
  f16* WoT = (f16*)(ws + 64 * MB);
  f16* q_h = (f16*)(ws + 72 * MB);
  f16* k_h = (f16*)(ws + 80 * MB);
  float* gate = (float*)(ws + 88 * MB);
  float2* mlbuf = (float2*)(ws + 88 * MB + 131072);
  f16* attn = q_raw;
  const f16* BT_all = WqT;                 // contiguous [6144][2048]
  f16* Call = q_raw;                       // contiguous 3x [2048][2048]
  float* Opart = (float*)(ws + 8 * MB);    // 24 MB (flash->merge)
  float* P0 = (float*)(ws + 8 * MB);       // 16 MB (out_sk->add)
  float* P1 = (float*)(ws + 40 * MB);      // 16 MB

  dim3 tb(32, 8);
  prep_all<<<dim3(64, 32, 6), tb, 0, stream>>>(Wq, Wk, Wv, Wo, hidden,
                                               WqT, WkT, WvT, WoT, hidh, gate);
  gemm_qkv192<<<dim3(32, 8), 512, 0, stream>>>(hidh, BT_all, Call);
  post_qkv<<<8192, 256, 0, stream>>>(q_raw, k_raw, qw, kw, pos, q_h, k_h, v_h, vT);
  flash_kernel<<<960, 256, 0, stream>>>(q_h, k_h, vT, gate, attn, Opart, mlbuf);
  merge_chunks<<<320, 256, 0, stream>>>(Opart, mlbuf, attn);
  gemm_out_sk<<<dim3(16, 16, 2), 256, 0, stream>>>(attn, WoT, P0, P1);
  add_out<<<4096, 256, 0, stream>>>(P0, P1, (float*)d_out);
}

// Round 9
// 322.961 us; speedup vs baseline: 1.0933x; 1.0933x over previous
//
#include <hip/hip_runtime.h>

typedef _Float16 f16;
typedef __attribute__((ext_vector_type(8))) _Float16 half8;
typedef __attribute__((ext_vector_type(4))) _Float16 half4v;
typedef __attribute__((ext_vector_type(4))) float floatx4;

#define T_DIM 2048
#define HID   2048
#define NH    16
#define HD    128
#define QG_LD 2064
#define SM_SCALE 0.08838834764831845f   // 1/sqrt(128)
#define NEG_BIG  -1e30f

// ---------------------------------------------------------------- async copy
__device__ __forceinline__ void async16(const void* g, void* l) {
  __builtin_amdgcn_global_load_lds((const __attribute__((address_space(1))) void*)g,
                                   (__attribute__((address_space(3))) void*)l, 16, 0, 0);
}

// ================================================= fused prep v5: transposes + convert + gate
// Grid (64, 32, 6).
// z=0..3: Wq/Wk/Wv/Wo fp32->f16 transpose, 64(K)x32(N) tiles, f16-pair u32 packing.
// z=4: hidden f32->f16 convert. z=5: gate fp64 dot (sign only) — the r7-measured version:
// contiguous-k lanes (one full 64B weight line per lane), padded LDS tree (no conflicts).
// v4's LDS-free gate REGRESSED 58->88us: column-split across waves made every wave touch
// all 2048 weight lines (4x line requests). Occupancy was never the binding constraint.
__global__ __launch_bounds__(256) void prep_all(const float* __restrict__ Wq,
                                                const float* __restrict__ Wk,
                                                const float* __restrict__ Wv,
                                                const float* __restrict__ Wo,
                                                const float* __restrict__ hidden,
                                                f16* __restrict__ WqT, f16* __restrict__ WkT,
                                                f16* __restrict__ WvT, f16* __restrict__ WoT,
                                                f16* __restrict__ hidh, float* __restrict__ gate) {
  __shared__ __align__(16) char smem[34816];
  const int z = blockIdx.z;
  const int tx = threadIdx.x, ty = threadIdx.y;
  const int tid = ty * 32 + tx;
  if (z == 4) {
    const int lb = blockIdx.y * 64 + blockIdx.x;   // 0..2047
#pragma unroll
    for (int e = 0; e < 2; ++e) {
      const int i = lb * 2048 + e * 1024 + tid * 4;
      const float4 v = *(const float4*)(hidden + i);
      half4v o;
      o.x = (f16)v.x; o.y = (f16)v.y; o.z = (f16)v.z; o.w = (f16)v.w;
      *(half4v*)(hidh + i) = o;
    }
    return;
  }
  if (z == 5) {
    double (*red)[17] = (double (*)[17])smem;   // 256*17*8 = 34816 B (pad -> no 32-way conflicts)
    const int t = blockIdx.y * 64 + blockIdx.x; // 0..2047
    double sums[16];
#pragma unroll
    for (int h2 = 0; h2 < 16; ++h2) sums[h2] = 0.0;
    const float* hrow = hidden + (size_t)t * HID;
    for (int k = tid; k < HID; k += 256) {
      const double hv = (double)hrow[k];
      const float* wr = Wq + (size_t)k * QG_LD + 2048;   // 16B-aligned
      const float4 w0 = *(const float4*)(wr);
      const float4 w1 = *(const float4*)(wr + 4);
      const float4 w2 = *(const float4*)(wr + 8);
      const float4 w3 = *(const float4*)(wr + 12);
      sums[0]  += hv * (double)w0.x; sums[1]  += hv * (double)w0.y;
      sums[2]  += hv * (double)w0.z; sums[3]  += hv * (double)w0.w;
      sums[4]  += hv * (double)w1.x; sums[5]  += hv * (double)w1.y;
      sums[6]  += hv * (double)w1.z; sums[7]  += hv * (double)w1.w;
      sums[8]  += hv * (double)w2.x; sums[9]  += hv * (double)w2.y;
      sums[10] += hv * (double)w2.z; sums[11] += hv * (double)w2.w;
      sums[12] += hv * (double)w3.x; sums[13] += hv * (double)w3.y;
      sums[14] += hv * (double)w3.z; sums[15] += hv * (double)w3.w;
    }
#pragma unroll
    for (int h2 = 0; h2 < 16; ++h2) red[tid][h2] = sums[h2];
    __syncthreads();
    for (int st = 128; st > 0; st >>= 1) {
      if (tid < st) {
#pragma unroll
        for (int h2 = 0; h2 < 16; ++h2) red[tid][h2] += red[tid + st][h2];
      }
      __syncthreads();
    }
    if (tid < 16) gate[(size_t)t * 16 + tid] = (red[0][tid] > 0.0) ? 1.f : 0.f;
    return;
  }
  // z = 0..3: fp32 -> f16 transpose with pair packing
  unsigned (*tile)[33] = (unsigned (*)[33])smem;  // 32*33*4 = 4224 B
  const float* src = (z == 0) ? Wq : ((z == 1) ? Wk : ((z == 2) ? Wv : Wo));
  const int ld = (z == 0) ? QG_LD : 2048;
  f16* dst = (z == 0) ? WqT : ((z == 1) ? WkT : ((z == 2) ? WvT : WoT));
  const int nb = blockIdx.x * 32;                 // N block (32 cols)
  const int kb = blockIdx.y * 64;                 // K block (64 rows = 32 pairs)
#pragma unroll
  for (int i = 0; i < 4; ++i) {
    const int kp = ty + 8 * i;                    // pair index 0..31
    const float lo = src[(size_t)(kb + 2 * kp) * ld + nb + tx];
    const float hi = src[(size_t)(kb + 2 * kp + 1) * ld + nb + tx];
    union { f16 h[2]; unsigned u; } cv;
    cv.h[0] = (f16)lo; cv.h[1] = (f16)hi;
    tile[kp][tx] = cv.u;
  }
  __syncthreads();
#pragma unroll
  for (int i = 0; i < 4; ++i) {
    const int n = ty + 8 * i;                     // output row within N-block
    *(unsigned*)&dst[(size_t)(nb + n) * HID + kb + 2 * tx] = tile[tx][n];
  }
}

// ================================================= fused post-QKV: RMSNorm+RoPE  |  V transpose
// blocks 0..4095: norm_rope (q & k). blocks 4096..8191: f16 V transpose (32x32 tiles).
// v2: cs/sn depend only on (t, dh<64) -> threads 0..63 fill a 512B LDS trig table once
// (same expressions, bitwise-identical values); element loop reads it. Removes 31/32 of
// the sincosf+expf work (2048 -> 64 per block).
__global__ __launch_bounds__(256) void post_qkv(const f16* __restrict__ qsrc, const f16* __restrict__ ksrc,
                                                const float* __restrict__ qw, const float* __restrict__ kw,
                                                const int* __restrict__ pos,
                                                f16* __restrict__ qdst, f16* __restrict__ kdst,
                                                const f16* __restrict__ vsrc, f16* __restrict__ vdst) {
  __shared__ __align__(16) char smem[9728];
  const int b = blockIdx.x;
  const int tid = threadIdx.x;
  if (b >= 4096) {
    f16 (*tile)[33] = (f16 (*)[33])smem;        // 32*33*2 = 2112 B
    const int u = b - 4096;
    const int bx = (u & 63) * 32, by = (u >> 6) * 32;
    const int tx = tid & 31, ty = tid >> 5;
#pragma unroll
    for (int i = 0; i < 4; ++i)
      tile[ty + 8 * i][tx] = vsrc[(size_t)(by + ty + 8 * i) * T_DIM + bx + tx];
    __syncthreads();
#pragma unroll
    for (int i = 0; i < 4; ++i)
      vdst[(size_t)(bx + ty + 8 * i) * T_DIM + by + tx] = tile[tx][ty + 8 * i];
    return;
  }
  float* row = (float*)smem;                    // 2048 f32 = 8192 B
  float* red = (float*)(smem + 8192);           // 256 f32 = 1024 B
  float2* trig = (float2*)(smem + 9216);        // 64 float2 = 512 B
  const int t = b & 2047, sel = b >> 11;
  const f16* s = (sel ? ksrc : qsrc) + (size_t)t * HID;
  const float* w = sel ? kw : qw;
  f16* dst = sel ? kdst : qdst;
  const float p = (float)pos[t];
  if (tid < 64) {
    const float inv = __expf(-(float)tid * 0.20503692772194388f);
    float cs, sn;
    sincosf(p * inv, &sn, &cs);
    trig[tid] = float2{cs, sn};
  }
  float ss = 0.f;
#pragma unroll
  for (int e = 0; e < 8; ++e) {
    float v = (float)s[tid + 256 * e];
    row[tid + 256 * e] = v;
    ss += v * v;
  }
  red[tid] = ss;
  __syncthreads();
  for (int st = 128; st > 0; st >>= 1) {
    if (tid < st) red[tid] += red[tid + st];
    __syncthreads();
  }
  const float scl = rsqrtf(red[0] * (1.f / 2048.f) + 1e-6f);
#pragma unroll
  for (int e = 0; e < 8; ++e) {
    const int idx = tid + 256 * e;
    const int d = idx & 127;
    const int dh = d & 63;
    const int pidx = (d < 64) ? idx + 64 : idx - 64;
    const float xn = row[idx] * scl * w[idx];
    const float xp = row[pidx] * scl * w[pidx];
    const float2 t2 = trig[dh];
    const float cs = t2.x, sn = t2.y;
    const float o = (d < 64) ? (xn * cs - xp * sn) : (xn * cs + xp * sn);
    dst[(size_t)t * HID + idx] = (f16)o;
  }
}

#define LGKM0() asm volatile("s_waitcnt lgkmcnt(0)" ::: "memory")
#define BAR()   __builtin_amdgcn_s_barrier()
#define PRIO(x) __builtin_amdgcn_s_setprio(x)

// ------------------------------------------------- GEMM 128x128xBK64, double-buffered (gemm_out_sk)
__device__ __forceinline__ void gemm_issue(const f16* __restrict__ A, const f16* __restrict__ Bt,
                                           char* As, char* Bs, int m0, int n0, int k0,
                                           int wave, int srow, int scol) {
#pragma unroll
  for (int i = 0; i < 4; ++i) {
    async16(A + (size_t)(m0 + 32 * i + srow) * 2048 + k0 + scol, As + 4096 * i + 1024 * wave);
    async16(Bt + (size_t)(n0 + 32 * i + srow) * 2048 + k0 + scol, Bs + 4096 * i + 1024 * wave);
  }
}

__device__ __forceinline__ void gemm_core_db(const f16* __restrict__ A, const f16* __restrict__ Bt,
                                             f16* As, f16* Bs, floatx4 (&acc)[4][4],
                                             int kbase, int klen) {
  const int tid = threadIdx.x;
  const int lane = tid & 63, wave = tid >> 6;
  const int m0 = blockIdx.y * 128, n0 = blockIdx.x * 128;
  const int mo = (wave >> 1) * 64, no = (wave & 1) * 64;
  const int cn = lane & 15, q16 = lane >> 4;
  const int srow = 8 * wave + (lane >> 3);
  const int scol = (lane & 7) * 8;
  gemm_issue(A, Bt, (char*)As, (char*)Bs, m0, n0, kbase, wave, srow, scol);
  int cur = 0;
  for (int k0 = kbase; k0 < kbase + klen; k0 += 64) {
    __syncthreads();
    if (k0 + 64 < kbase + klen)
      gemm_issue(A, Bt, (char*)(As + (cur ^ 1) * 8192), (char*)(Bs + (cur ^ 1) * 8192),
                 m0, n0, k0 + 64, wave, srow, scol);
    const f16* as = As + cur * 8192;
    const f16* bs = Bs + cur * 8192;
#pragma unroll
    for (int kk = 0; kk < 64; kk += 32) {
      half8 av[4], bv[4];
#pragma unroll
      for (int i = 0; i < 4; ++i) av[i] = *(const half8*)&as[(mo + i * 16 + cn) * 64 + kk + q16 * 8];
#pragma unroll
      for (int i = 0; i < 4; ++i) bv[i] = *(const half8*)&bs[(no + i * 16 + cn) * 64 + kk + q16 * 8];
#pragma unroll
      for (int i = 0; i < 4; ++i)
#pragma unroll
        for (int j = 0; j < 4; ++j)
          acc[i][j] = __builtin_amdgcn_mfma_f32_16x16x32_f16(av[i], bv[j], acc[i][j], 0, 0, 0);
    }
    cur ^= 1;
  }
}

// ================================================= 256x192 8-phase fused QKV GEMM
// One GEMM: M=2048, N=6144 (WqT|WkT|WvT contiguous), K=2048. BM=256, BN=192, BK=64.
// Grid (32,8) = 256 blocks. 8 waves (2Mx4N), wave tile 128x48. 112 KiB LDS dbuf.
#define NKT 32

__device__ __forceinline__ void stage_piece(const f16* __restrict__ src, int row0, int kcol,
                                            char* dst, int wv, int lane) {
  const int rsw = lane >> 3;
  const int csw = ((lane & 7) ^ rsw) << 3;
  async16(src + (size_t)(row0 + wv * 8 + rsw) * 2048 + kcol + csw, dst + wv * 1024);
}

template <int MQ, int KH>
__device__ __forceinline__ void ld_a1(half8 (&a)[4], const f16* As, int wm, int cn, int q16) {
#pragma unroll
  for (int rf = 0; rf < 4; ++rf) {
    const int R = wm * 128 + MQ * 64 + rf * 16 + cn;
    a[rf] = *(const half8*)&As[R * 64 + (((KH * 4 + q16) ^ (cn & 7)) << 3)];
  }
}

template <int KH>
__device__ __forceinline__ void ld_b3(half8 (&b)[3], const f16* Bs, int wn, int cn, int q16) {
#pragma unroll
  for (int cf = 0; cf < 3; ++cf) {
    const int S = wn * 48 + cf * 16 + cn;
    b[cf] = *(const half8*)&Bs[S * 64 + (((KH * 4 + q16) ^ (cn & 7)) << 3)];
  }
}

template <int MQ>
__device__ __forceinline__ void mma12(floatx4 (&acc)[8][3], const half8 (&a)[4], const half8 (&b)[3]) {
#pragma unroll
  for (int rf = 0; rf < 4; ++rf)
#pragma unroll
    for (int cf = 0; cf < 3; ++cf)
      acc[MQ * 4 + rf][cf] = __builtin_amdgcn_mfma_f32_16x16x32_f16(
          a[rf], b[cf], acc[MQ * 4 + rf][cf], 0, 0, 0);
}

#define QKV_A(q, kt, buf) stage_piece(A,  m0 + (q) * 64, (kt) * 64, ldsb + (buf) * 57344 + (q) * 8192, wv, lane)
#define QKV_B(p, kt, buf) stage_piece(BT, n0 + (p) * 64, (kt) * 64, ldsb + (buf) * 57344 + 32768 + (p) * 8192, wv, lane)

__global__ __launch_bounds__(512, 2) void gemm_qkv192(const f16* __restrict__ A,
                                                      const f16* __restrict__ BT,   // [6144][2048]
                                                      f16* __restrict__ Call) {     // 3x [2048][2048] contiguous
  __shared__ __align__(16) f16 lds[57344];  // 112 KiB
  char* const ldsb = (char*)lds;
  const int tid = threadIdx.x;
  const int lane = tid & 63, wv = tid >> 6;
  const int wm = wv >> 2, wn = wv & 3;
  const int q16 = lane >> 4, cn = lane & 15;
  const int m0 = blockIdx.y * 256, n0 = blockIdx.x * 192;

  floatx4 acc[8][3] = {};
  half8 a[4], b0[3], b1[3];

  // prologue: t0 all 7 pieces, then t1 in steady issue order
  QKV_B(0, 0, 0); QKV_B(1, 0, 0); QKV_B(2, 0, 0); QKV_A(0, 0, 0); QKV_A(2, 0, 0);
  QKV_A(1, 0, 0); QKV_A(3, 0, 0);
  QKV_B(0, 1, 1); QKV_B(1, 1, 1); QKV_B(2, 1, 1); QKV_A(0, 1, 1); QKV_A(2, 1, 1);
  QKV_A(1, 1, 1); QKV_A(3, 1, 1);
  asm volatile("s_waitcnt vmcnt(7)" ::: "memory");
  BAR();

  for (int t = 0; t < NKT; ++t) {
    const int pb = t & 1;
    const f16* As = lds + pb * 28672;
    const f16* Bs = As + 16384;
    // ---- P1 (MQ0, kh0)
    ld_b3<0>(b0, Bs, wn, cn, q16);
    ld_a1<0, 0>(a, As, wm, cn, q16);
    if (t >= 1 && t + 1 < NKT) QKV_A(1, t + 1, pb ^ 1);
    asm volatile("s_waitcnt vmcnt(6)" ::: "memory");
    BAR(); LGKM0();
    PRIO(1); mma12<0>(acc, a, b0); PRIO(0);
    BAR();
    // ---- P2 (MQ1, kh0)
    ld_a1<1, 0>(a, As, wm, cn, q16);
    if (t >= 1 && t + 1 < NKT) QKV_A(3, t + 1, pb ^ 1);
    BAR(); LGKM0();
    PRIO(1); mma12<1>(acc, a, b0); PRIO(0);
    BAR();
    // ---- P3 (MQ0, kh1)
    ld_b3<1>(b1, Bs, wn, cn, q16);
    ld_a1<0, 1>(a, As, wm, cn, q16);
    BAR(); LGKM0();
    PRIO(1); mma12<0>(acc, a, b1); PRIO(0);
    BAR();
    // ---- P4 (MQ1, kh1)
    ld_a1<1, 1>(a, As, wm, cn, q16);
    if (t + 2 < NKT) {
      QKV_B(0, t + 2, pb); QKV_B(1, t + 2, pb); QKV_B(2, t + 2, pb);
      QKV_A(0, t + 2, pb); QKV_A(2, t + 2, pb);
      asm volatile("s_waitcnt vmcnt(7)" ::: "memory");
    } else if (t == NKT - 2) {
      asm volatile("s_waitcnt vmcnt(0)" ::: "memory");
    }
    BAR(); LGKM0();
    PRIO(1); mma12<1>(acc, a, b1); PRIO(0);
    BAR();
  }

  // epilogue: output buffer = global col >> 11 (16-col frags never straddle: bases 16-aligned)
  const int r0 = q16 * 4;
#pragma unroll
  for (int j = 0; j < 3; ++j) {
    const int cb = n0 + wn * 48 + j * 16;
    f16* Cj = Call + ((size_t)(cb >> 11) << 22) + (cb & 2047) + cn;
#pragma unroll
    for (int i = 0; i < 8; ++i)
#pragma unroll
      for (int r = 0; r < 4; ++r)
        Cj[(size_t)(m0 + wm * 128 + i * 16 + r0 + r) * 2048] = (f16)acc[i][j][r];
  }
}

// split-K=2 attention-output GEMM: z picks K-half, writes fp32 partial (r3-proven)
__global__ __launch_bounds__(256, 2) void gemm_out_sk(const f16* __restrict__ A, const f16* __restrict__ Bt,
                                                      float* __restrict__ P0, float* __restrict__ P1) {
  __shared__ __align__(16) f16 As[2 * 128 * 64];
  __shared__ __align__(16) f16 Bs[2 * 128 * 64];
  const int z = blockIdx.z;
  floatx4 acc[4][4] = {};
  gemm_core_db(A, Bt, As, Bs, acc, z * 1024, 1024);
  float* C = z ? P1 : P0;
  const int lane = threadIdx.x & 63, wave = threadIdx.x >> 6;
  const int mb = blockIdx.y * 128 + (wave >> 1) * 64;
  const int nb = blockIdx.x * 128 + (wave & 1) * 64;
  const int r0 = (lane >> 4) * 4, cn = lane & 15;
#pragma unroll
  for (int i = 0; i < 4; ++i)
#pragma unroll
    for (int j = 0; j < 4; ++j)
#pragma unroll
      for (int r = 0; r < 4; ++r)
        C[(size_t)(mb + i * 16 + r0 + r) * 2048 + nb + j * 16 + cn] = acc[i][j][r];
}

__global__ __launch_bounds__(256) void add_out(const float* __restrict__ P0, const float* __restrict__ P1,
                                               float* __restrict__ out) {
  const int i = (blockIdx.x * 256 + threadIdx.x) * 4;
  const float4 a = *(const float4*)(P0 + i);
  const float4 b = *(const float4*)(P1 + i);
  float4 o;
  o.x = a.x + b.x; o.y = a.y + b.y; o.z = a.z + b.z; o.w = a.w + b.w;
  *(float4*)(out + i) = o;
}

// ------------------------------------------------- dual flash attention v5: split-K load balance
__global__ __launch_bounds__(256, 2) void flash_kernel(const f16* __restrict__ Qg, const f16* __restrict__ Kg,
                                                       const f16* __restrict__ VTg, const float* __restrict__ gate,
                                                       f16* __restrict__ Oa, float* __restrict__ Opart,
                                                       float2* __restrict__ ml) {
  __shared__ __align__(16) f16 Ks[2][64 * 128];    // [s][d], granule-swizzled
  __shared__ __align__(16) f16 VTs[2][128 * 64];   // [d][s], granule-swizzled
  __shared__ __align__(16) f16 Ps[4][16][72];      // wave-private, 144B stride

  const int tid = threadIdx.x;
  const int lane = tid & 63, wv = tid >> 6;
  const int q16 = lane >> 4, cn = lane & 15;
  const int r0 = q16 * 4;

  // ---- chunk decode: p -> (h, qt, [kb,ke], slot) ; ordered big-work-first
  const int p = blockIdx.x;
  const int o = p >> 4;
  const int h = p & 15;
  int qt, nsp, piece, slot_o;
  if (o < 24)      { qt = 31 - o / 3;        nsp = 3; piece = o % 3;        slot_o = o; }
  else if (o < 36) { qt = 35 - o;            nsp = 1; piece = 0;            slot_o = 0; }
  else             { int u = o - 36; qt = 23 - (u >> 1); nsp = 2; piece = u & 1; slot_o = 24 + u; }
  const int L = qt + 1;
  const int base = L / nsp, rem = L % nsp;
  const int kb = piece * base + (piece < rem ? piece : rem);
  const int ke = kb + base + (piece < rem ? 1 : 0) - 1;
  const bool split = (nsp > 1);
  const int slot = h * 48 + slot_o;
  const int t0 = qt * 64;

  bool gbit[4];
#pragma unroll
  for (int r = 0; r < 4; ++r)
    gbit[r] = gate[(size_t)(t0 + wv * 16 + r0 + r) * NH + h] > 0.5f;

  half8 qa[4];
#pragma unroll
  for (int i = 0; i < 4; ++i)
    qa[i] = *(const half8*)(Qg + (size_t)(t0 + 16 * wv + cn) * HID + h * HD + 32 * i + q16 * 8);

  {
    const int sb = kb * 64;
#pragma unroll
    for (int i = 0; i < 4; ++i) {
      const int rk = 16 * i + 4 * wv + q16;
      async16(Kg + (size_t)(sb + rk) * HID + h * HD + ((cn ^ (rk & 7)) << 3),
              (char*)Ks[0] + 4096 * i + 1024 * wv);
      const int rv = 32 * i + 8 * wv + (lane >> 3);
      async16(VTg + (size_t)(h * HD + rv) * T_DIM + sb + (((lane & 7) ^ (lane >> 3)) << 3),
              (char*)VTs[0] + 4096 * i + 1024 * wv);
    }
  }

  floatx4 og[8] = {};
  floatx4 lacc = {0.f, 0.f, 0.f, 0.f};
  float mg[4];
#pragma unroll
  for (int r = 0; r < 4; ++r) mg[r] = NEG_BIG;

  const half8 ones = {(f16)1, (f16)1, (f16)1, (f16)1, (f16)1, (f16)1, (f16)1, (f16)1};

  int cur = 0;
  for (int kt = kb; kt <= ke; ++kt) {
    const int s0 = kt * 64;
    __syncthreads();
    if (kt < ke) {
      const int sn = s0 + 64;
#pragma unroll
      for (int i = 0; i < 4; ++i) {
        const int rk = 16 * i + 4 * wv + q16;
        async16(Kg + (size_t)(sn + rk) * HID + h * HD + ((cn ^ (rk & 7)) << 3),
                (char*)Ks[cur ^ 1] + 4096 * i + 1024 * wv);
        const int rv = 32 * i + 8 * wv + (lane >> 3);
        async16(VTg + (size_t)(h * HD + rv) * T_DIM + sn + (((lane & 7) ^ (lane >> 3)) << 3),
                (char*)VTs[cur ^ 1] + 4096 * i + 1024 * wv);
      }
    }

    // S = Q K^T : wave wv owns rows [16wv, 16wv+16)
    floatx4 sacc[4] = {};
    PRIO(1);
#pragma unroll
    for (int i = 0; i < 4; ++i)
#pragma unroll
      for (int nt = 0; nt < 4; ++nt) {
        half8 b = *(const half8*)&Ks[cur][(nt * 16 + cn) * 128 + (((4 * i + q16) ^ (cn & 7)) << 3)];
        sacc[nt] = __builtin_amdgcn_mfma_f32_16x16x32_f16(qa[i], b, sacc[nt], 0, 0, 0);
      }
    PRIO(0);

    const bool diag = (kt == qt);

    float pe[4][4];
#pragma unroll
    for (int nt = 0; nt < 4; ++nt)
#pragma unroll
      for (int r = 0; r < 4; ++r) {
        float x = sacc[nt][r] * SM_SCALE;
        if (diag && (s0 + nt * 16 + cn > t0 + wv * 16 + r0 + r)) x = NEG_BIG;
        pe[nt][r] = x;
      }

    float rmax[4];
#pragma unroll
    for (int r = 0; r < 4; ++r)
      rmax[r] = fmaxf(fmaxf(pe[0][r], pe[1][r]), fmaxf(pe[2][r], pe[3][r]));
#pragma unroll
    for (int off = 1; off < 16; off <<= 1)
#pragma unroll
      for (int r = 0; r < 4; ++r) rmax[r] = fmaxf(rmax[r], __shfl_xor(rmax[r], off, 64));

    // defer-rescale: when no row max grows, alpha == 1.0 exactly -> skip is bitwise identical
    const bool grow = (rmax[0] > mg[0]) | (rmax[1] > mg[1]) | (rmax[2] > mg[2]) | (rmax[3] > mg[3]);
    if (__any(grow)) {
      float alpha[4];
#pragma unroll
      for (int r = 0; r < 4; ++r) {
        const float mn = fmaxf(mg[r], rmax[r]);
        alpha[r] = __expf(mg[r] - mn);
        mg[r] = mn;
      }
#pragma unroll
      for (int dt = 0; dt < 8; ++dt)
#pragma unroll
        for (int r = 0; r < 4; ++r) og[dt][r] *= alpha[r];
#pragma unroll
      for (int r = 0; r < 4; ++r) lacc[r] *= alpha[r];
    }

    // exp, gate/window select, store P_sel (wave-private -> no barrier)
#pragma unroll
    for (int nt = 0; nt < 4; ++nt)
#pragma unroll
      for (int r = 0; r < 4; ++r) {
        const float e = __expf(pe[nt][r] - mg[r]);   // causal-masked -> 0
        const int tt = t0 + wv * 16 + r0 + r;
        const int s = s0 + nt * 16 + cn;
        const bool keep = gbit[r] || (tt - s < 128);
        Ps[wv][r0 + r][nt * 16 + cn] = keep ? (f16)e : (f16)0.f;
      }

    // PV + row-sum: A = own P_sel rows
    PRIO(1);
#pragma unroll
    for (int kk = 0; kk < 64; kk += 32) {
      half8 a = *(const half8*)&Ps[wv][cn][kk + q16 * 8];
#pragma unroll
      for (int dt = 0; dt < 8; ++dt) {
        half8 b = *(const half8*)&VTs[cur][(dt * 16 + cn) * 64 + ((((kk >> 3) + q16) ^ (cn & 7)) << 3)];
        og[dt] = __builtin_amdgcn_mfma_f32_16x16x32_f16(a, b, og[dt], 0, 0, 0);
      }
      lacc = __builtin_amdgcn_mfma_f32_16x16x32_f16(a, ones, lacc, 0, 0, 0);
    }
    PRIO(0);
    cur ^= 1;
  }

  if (!split) {
#pragma unroll
    for (int dt = 0; dt < 8; ++dt)
#pragma unroll
      for (int r = 0; r < 4; ++r) {
        const float v = og[dt][r] / lacc[r];
        Oa[(size_t)(t0 + wv * 16 + r0 + r) * HID + h * HD + dt * 16 + cn] = (f16)v;
      }
  } else {
    float* ob = Opart + ((size_t)slot * 64 + wv * 16) * 128;
#pragma unroll
    for (int dt = 0; dt < 8; ++dt)
#pragma unroll
      for (int r = 0; r < 4; ++r)
        ob[(r0 + r) * 128 + dt * 16 + cn] = og[dt][r];
    if (cn == 0) {
      float2* mlp = ml + slot * 64 + wv * 16;
#pragma unroll
      for (int r = 0; r < 4; ++r) mlp[r0 + r] = float2{mg[r], lacc[r]};
    }
  }
}

// ------------------------------------------------- merge split-K partials (qt>=12 only)
__global__ __launch_bounds__(256) void merge_chunks(const float* __restrict__ Opart,
                                                    const float2* __restrict__ ml,
                                                    f16* __restrict__ attn) {
  const int b = blockIdx.x;           // 320 = 16 heads x 20 q-tiles (qt 12..31)
  const int h = b & 15, v = b >> 4;
  const int qt = 12 + v;
  const int n = (qt >= 24) ? 3 : 2;
  const int s0 = (qt >= 24) ? (h * 48 + 3 * (31 - qt)) : (h * 48 + 24 + 2 * (23 - qt));
  const int tid = threadIdx.x;
  const int row = tid >> 2;           // 0..63
  const int cq = (tid & 3) * 32;

  float m = NEG_BIG, mv[3], lv[3];
#pragma unroll
  for (int c = 0; c < 3; ++c) {
    if (c < n) {
      const float2 x = ml[(s0 + c) * 64 + row];
      mv[c] = x.x; lv[c] = x.y;
      m = fmaxf(m, x.x);
    }
  }
  float e[3], denom = 0.f;
#pragma unroll
  for (int c = 0; c < 3; ++c) {
    if (c < n) {
      e[c] = __expf(mv[c] - m);
      denom += e[c] * lv[c];
    }
  }
  const float inv = 1.f / denom;
  f16* out = attn + (size_t)(qt * 64 + row) * 2048 + h * 128 + cq;
#pragma unroll
  for (int i = 0; i < 32; i += 4) {
    float4 acc = {0.f, 0.f, 0.f, 0.f};
#pragma unroll
    for (int c = 0; c < 3; ++c) {
      if (c < n) {
        const float4 a = *(const float4*)(Opart + ((size_t)(s0 + c) * 64 + row) * 128 + cq + i);
        acc.x += e[c] * a.x; acc.y += e[c] * a.y; acc.z += e[c] * a.z; acc.w += e[c] * a.w;
      }
    }
    out[i + 0] = (f16)(acc.x * inv);
    out[i + 1] = (f16)(acc.y * inv);
    out[i + 2] = (f16)(acc.z * inv);
    out[i + 3] = (f16)(acc.w * inv);
  }
}

// ------------------------------------------------------------------ host
extern "C" void kernel_launch(void* const* d_in, const int* in_sizes, int n_in,
                              void* d_out, int out_size, void* d_ws, size_t ws_size,
                              hipStream_t stream) {
  const float* hidden = (const float*)d_in[0];
  const int* pos = (const int*)d_in[1];
  const float* Wq = (const float*)d_in[2];
  const float* Wk = (const float*)d_in[3];
  const float* Wv = (const float*)d_in[4];
  const float* Wo = (const float*)d_in[5];
  const float* qw = (const float*)d_in[6];
  const float* kw = (const float*)d_in[7];

  char* ws = (char*)d_ws;
  const size_t MB = 1ull << 20;
  // Layout (peak ~88.5 MB):
  //  0- 8 WqT (rows 0-2047 of BT_all)
  //  8-16 WkT                     -> dead after QKV: Opart (8-32), later P0 (8-24)
  // 16-24 WvT
  // 24-32 hidh                    -> dead after QKV
  // 32-40 q_raw (Call buf 0)      -> reused as attn after norm
  // 40-48 k_raw (Call buf 1)      -> dead after post_qkv: P1 (40-56)
  // 48-56 v_h   (Call buf 2)      -> dead after post_qkv
  // 56-64 vT                      -> dead after flash
  // 64-72 WoT                     (written at prep, live until gemm_out_sk)
  // 72-80 q_h, 80-88 k_h          -> dead after flash
  // 88.0-88.125 gate, 88.125-88.5 mlbuf
  f16* WqT = (f16*)(ws + 0 * MB);
  f16* WkT = (f16*)(ws + 8 * MB);
  f16* WvT = (f16*)(ws + 16 * MB);
  f16* hidh = (f16*)(ws + 24 * MB);
  f16* q_raw = (f16*)(ws + 32 * MB);
  f16* k_raw = (f16*)(ws + 40 * MB);
  f16* v_h = (f16*)(ws + 48 * MB);
  f16* vT = (f16*)(ws + 56 * MB);
  f16* WoT = (f16*)(ws + 64 * MB);
  f16* q_h = (f16*)(ws + 72 * MB);
  f16* k_h = (f16*)(ws + 80 * MB);
  float* gate = (float*)(ws + 88 * MB);
  float2* mlbuf = (float2*)(ws + 88 * MB + 131072);
  f16* attn = q_raw;
  const f16* BT_all = WqT;                 // contiguous [6144][2048]
  f16* Call = q_raw;                       // contiguous 3x [2048][2048]
  float* Opart = (float*)(ws + 8 * MB);    // 24 MB (flash->merge)
  float* P0 = (float*)(ws + 8 * MB);       // 16 MB (out_sk->add)
  float* P1 = (float*)(ws + 40 * MB);      // 16 MB

  dim3 tb(32, 8);
  prep_all<<<dim3(64, 32, 6), tb, 0, stream>>>(Wq, Wk, Wv, Wo, hidden,
                                               WqT, WkT, WvT, WoT, hidh, gate);
  gemm_qkv192<<<dim3(32, 8), 512, 0, stream>>>(hidh, BT_all, Call);
  post_qkv<<<8192, 256, 0, stream>>>(q_raw, k_raw, qw, kw, pos, q_h, k_h, v_h, vT);
  flash_kernel<<<960, 256, 0, stream>>>(q_h, k_h, vT, gate, attn, Opart, mlbuf);
  merge_chunks<<<320, 256, 0, stream>>>(Opart, mlbuf, attn);
  gemm_out_sk<<<dim3(16, 16, 2), 256, 0, stream>>>(attn, WoT, P0, P1);
  add_out<<<4096, 256, 0, stream>>>(P0, P1, (float*)d_out);
}